// Round 24
// baseline (319.567 us; speedup 1.0000x reference)
//
#include <hip/hip_runtime.h>

#define HIDDEN 1152
#define HEADS  16
#define HDIM   72
#define DPAD   96
#define NB     2
#define TT     4096
#define BT     (NB*TT)  // 8192

#define KSTR2  80      // attn K-tile row stride (shorts)
#define VOFF   5120    // attn V offset inside KV buffer (shorts)

typedef float  f32x4   __attribute__((ext_vector_type(4)));
typedef __bf16 bf16x8  __attribute__((ext_vector_type(8)));
typedef unsigned u32x4 __attribute__((ext_vector_type(4)));

static __device__ __forceinline__ unsigned pkbf(float a, float b){
    unsigned r;
    asm("v_cvt_pk_bf16_f32 %0, %1, %2" : "=v"(r) : "v"(a), "v"(b));
    return r;
}
static __device__ __forceinline__ unsigned short f2b(float f){
    return (unsigned short)pkbf(f, f);
}
static __device__ __forceinline__ void gld16(const unsigned short* g, unsigned short* l){
    __builtin_amdgcn_global_load_lds((const __attribute__((address_space(1))) void*)g,
                                     (__attribute__((address_space(3))) void*)l, 16, 0, 0);
}

__global__ __launch_bounds__(256) void k_convert_x(const float* __restrict__ x, unsigned short* __restrict__ xb){
    int i = (blockIdx.x*256 + threadIdx.x) * 4;
    float4 v = *reinterpret_cast<const float4*>(x + i);
    uint2 p; p.x = pkbf(v.x, v.y); p.y = pkbf(v.z, v.w);
    *reinterpret_cast<uint2*>(xb + i) = p;
}

// targeted pad-zeroing: Q d in [80,96) and K d in [72,80) (V pads feed discarded outputs)
__global__ __launch_bounds__(256) void k_padzero(unsigned short* __restrict__ Qp,
                                                 unsigned short* __restrict__ Kp){
    int row = blockIdx.x*256 + threadIdx.x;       // 131072 rows
    uint4 z = {0,0,0,0};
    unsigned short* q = Qp + (size_t)row*DPAD + 80;
    *reinterpret_cast<uint4*>(q)     = z;
    *reinterpret_cast<uint4*>(q + 8) = z;
    *reinterpret_cast<uint4*>(Kp + (size_t)row*DPAD + 72) = z;
}

// fused tiled transpose+convert for all 4 weights: w[k][n] (fp32) -> wt[n][k] (bf16)
__global__ __launch_bounds__(256) void k_wtrans(const float* __restrict__ wq, const float* __restrict__ wk,
                                                const float* __restrict__ wv, const float* __restrict__ wo,
                                                unsigned short* __restrict__ wt0){
    __shared__ __align__(16) unsigned short Ws[64][72];
    const int wi = blockIdx.x / 324, bi = blockIdx.x % 324;
    const float* w = wi==0 ? wq : (wi==1 ? wk : (wi==2 ? wv : wo));
    unsigned short* wt = wt0 + (size_t)wi*HIDDEN*HIDDEN;
    const int r0 = (bi / 18) * 64, c0 = (bi % 18) * 64;
    #pragma unroll
    for(int it=0; it<4; ++it){
        int idx = threadIdx.x + it*256;
        int r = idx >> 4, cq = (idx & 15) * 4;
        float4 v = *reinterpret_cast<const float4*>(w + (size_t)(r0+r)*HIDDEN + c0 + cq);
        uint2 p; p.x = pkbf(v.x, v.y); p.y = pkbf(v.z, v.w);
        *reinterpret_cast<uint2*>(&Ws[r][cq]) = p;
    }
    __syncthreads();
    #pragma unroll
    for(int it=0; it<4; ++it){
        int idx = threadIdx.x + it*256;
        int rr = idx >> 4, cq = (idx & 15) * 4;
        ushort4 o;
        o.x = Ws[cq+0][rr]; o.y = Ws[cq+1][rr]; o.z = Ws[cq+2][rr]; o.w = Ws[cq+3][rr];
        *reinterpret_cast<ushort4*>(wt + (size_t)(c0+rr)*HIDDEN + r0 + cq) = o;
    }
}

// Fused QKV GEMM, BK=64, double-buffered: issue loads(t+1) -> compute(t) -> ONE barrier.
__global__ __launch_bounds__(256, 2) void k_gemm_qkv(const unsigned short* __restrict__ A,
                                                     const unsigned short* __restrict__ WT,
                                                     const float* __restrict__ bq,
                                                     const float* __restrict__ bk,
                                                     const float* __restrict__ bv,
                                                     unsigned short* __restrict__ Qp,
                                                     unsigned short* __restrict__ Kp,
                                                     unsigned short* __restrict__ Vt,
                                                     float qscale){
    __shared__ __align__(16) unsigned short S[2][16384];      // [buf][As 8192 | Bs 8192] = 64 KB
    const int tid = threadIdx.x, lane = tid & 63, wid = tid >> 6;
    const int wm = wid >> 1, wn = wid & 1;
    const int half = lane >> 4, q16 = lane & 15;
    const int sw7 = q16 & 7;
    int lb = (blockIdx.x & 7) * 216 + (blockIdx.x >> 3);      // XCD-chunked swizzle (1728 = 8*216)
    const int m0 = (lb / 27) * 128;
    const int t9 = lb % 27;
    const int which = t9 / 9;                                  // 0=Q 1=K 2=V (block-uniform)
    const int n0g = t9 * 128;
    const int cc0 = (t9 % 9) * 128;
    const float* bias = which==0 ? bq : (which==1 ? bk : bv);
    const float scale = which==0 ? qscale : 1.0f;

    size_t aoff[4], boff[4];
    #pragma unroll
    for(int it=0; it<4; ++it){
        int c = tid + it*256;
        int row = c >> 3, ph = c & 7;
        int gsrc = ph ^ (row & 7);
        aoff[it] = (size_t)(m0  + row)*HIDDEN + gsrc*8;
        boff[it] = (size_t)(n0g + row)*HIDDEN + gsrc*8;
    }

    // prologue: stage k0=0 into buf 0
    #pragma unroll
    for(int it=0; it<4; ++it) gld16(A  + aoff[it], &S[0][(tid + it*256)*8]);
    #pragma unroll
    for(int it=0; it<4; ++it) gld16(WT + boff[it], &S[0][8192 + (tid + it*256)*8]);
    __syncthreads();

    f32x4 acc[4][4] = {};
    for(int t = 0; t < 18; ++t){
        const int cur = t & 1;
        if(t < 17){
            const int k1 = (t+1)*64;
            #pragma unroll
            for(int it=0; it<4; ++it) gld16(A  + aoff[it] + k1, &S[cur^1][(tid + it*256)*8]);
            #pragma unroll
            for(int it=0; it<4; ++it) gld16(WT + boff[it] + k1, &S[cur^1][8192 + (tid + it*256)*8]);
        }
        const unsigned short* As = S[cur];
        const unsigned short* Bs = S[cur] + 8192;
        #pragma unroll
        for(int kk=0; kk<2; ++kk){
            bf16x8 af[4], bf[4];
            #pragma unroll
            for(int mi=0;mi<4;++mi)
                af[mi] = *reinterpret_cast<const bf16x8*>(As + (wm*64+mi*16+q16)*64 + (((kk*4+half) ^ sw7)<<3));
            #pragma unroll
            for(int ni=0;ni<4;++ni)
                bf[ni] = *reinterpret_cast<const bf16x8*>(Bs + (wn*64+ni*16+q16)*64 + (((kk*4+half) ^ sw7)<<3));
            #pragma unroll
            for(int mi=0;mi<4;++mi)
                #pragma unroll
                for(int ni=0;ni<4;++ni)
                    acc[mi][ni] = __builtin_amdgcn_mfma_f32_16x16x32_bf16(af[mi], bf[ni], acc[mi][ni], 0,0,0);
        }
        __syncthreads();   // drains loads(t+1) (in flight across compute) + fences buf[cur] rewrite
    }
    if(which < 2){
        unsigned short* outp = which==0 ? Qp : Kp;
        #pragma unroll
        for(int mi=0;mi<4;++mi)
            #pragma unroll
            for(int ni=0;ni<4;++ni)
                #pragma unroll
                for(int j=0;j<4;++j){
                    int row = m0 + wm*64 + mi*16 + half*4 + j;
                    int col = cc0 + wn*64 + ni*16 + q16;
                    float v = (acc[mi][ni][j] + bias[col]) * scale;
                    int bb = row >> 12, t = row & 4095;
                    int hh = col / HDIM, d = col % HDIM;
                    outp[((size_t)((bb*HEADS + hh)*TT) + t)*DPAD + d] = f2b(v);
                }
    } else {
        // V: transpose 128x128 tile through LDS (two 64-row passes) for coalesced [d][t] stores
        unsigned short* Sv = S[0];
        #pragma unroll
        for(int ph=0; ph<2; ++ph){
            if(wm == ph){
                #pragma unroll
                for(int mi=0;mi<4;++mi)
                    #pragma unroll
                    for(int ni=0;ni<4;++ni)
                        #pragma unroll
                        for(int j=0;j<4;++j){
                            int rloc = mi*16 + half*4 + j;
                            int cloc = wn*64 + ni*16 + q16;
                            float v = acc[mi][ni][j] + bias[cc0 + cloc];
                            Sv[cloc*64 + (rloc ^ ((cloc&7)<<3))] = f2b(v);
                        }
            }
            __syncthreads();
            {
                int col = tid >> 1, seg = tid & 1;
                int gcol = cc0 + col, hh = gcol / HDIM, d = gcol % HDIM;
                int grow = m0 + ph*64 + seg*32;
                int bb = grow >> 12, t0 = grow & 4095;
                unsigned short* dst = Vt + ((size_t)((bb*HEADS + hh)*DPAD) + d)*TT + t0;
                #pragma unroll
                for(int kg=0; kg<4; ++kg){
                    uint4 v = *reinterpret_cast<const uint4*>(&Sv[col*64 + ((seg*32 + kg*8) ^ ((col&7)<<3))]);
                    *reinterpret_cast<uint4*>(dst + kg*8) = v;
                }
            }
            __syncthreads();
        }
    }
}

// O-projection GEMM, BK=64, double-buffered: fp32 out + bias
__global__ __launch_bounds__(256, 2) void k_gemm_o(const unsigned short* __restrict__ A,
                                                   const unsigned short* __restrict__ Bt,
                                                   const float* __restrict__ bias,
                                                   float* __restrict__ out){
    __shared__ __align__(16) unsigned short S[2][16384];      // [buf][As | Bs] = 64 KB
    const int tid = threadIdx.x, lane = tid & 63, wid = tid >> 6;
    const int wm = wid >> 1, wn = wid & 1;
    const int half = lane >> 4, q16 = lane & 15;
    const int sw7 = q16 & 7;
    int lb = (blockIdx.x & 7) * 72 + (blockIdx.x >> 3);       // XCD-chunked swizzle (576 = 8*72)
    const int n0 = (lb % 9) * 128, m0 = (lb / 9) * 128;

    size_t aoff[4], boff[4];
    #pragma unroll
    for(int it=0; it<4; ++it){
        int c = tid + it*256;
        int row = c >> 3, ph = c & 7;
        int gsrc = ph ^ (row & 7);
        aoff[it] = (size_t)(m0 + row)*HIDDEN + gsrc*8;
        boff[it] = (size_t)(n0 + row)*HIDDEN + gsrc*8;
    }

    #pragma unroll
    for(int it=0; it<4; ++it) gld16(A  + aoff[it], &S[0][(tid + it*256)*8]);
    #pragma unroll
    for(int it=0; it<4; ++it) gld16(Bt + boff[it], &S[0][8192 + (tid + it*256)*8]);
    __syncthreads();

    f32x4 acc[4][4] = {};
    for(int t = 0; t < 18; ++t){
        const int cur = t & 1;
        if(t < 17){
            const int k1 = (t+1)*64;
            #pragma unroll
            for(int it=0; it<4; ++it) gld16(A  + aoff[it] + k1, &S[cur^1][(tid + it*256)*8]);
            #pragma unroll
            for(int it=0; it<4; ++it) gld16(Bt + boff[it] + k1, &S[cur^1][8192 + (tid + it*256)*8]);
        }
        const unsigned short* As = S[cur];
        const unsigned short* Bs = S[cur] + 8192;
        #pragma unroll
        for(int kk=0; kk<2; ++kk){
            bf16x8 af[4], bf[4];
            #pragma unroll
            for(int mi=0;mi<4;++mi)
                af[mi] = *reinterpret_cast<const bf16x8*>(As + (wm*64+mi*16+q16)*64 + (((kk*4+half) ^ sw7)<<3));
            #pragma unroll
            for(int ni=0;ni<4;++ni)
                bf[ni] = *reinterpret_cast<const bf16x8*>(Bs + (wn*64+ni*16+q16)*64 + (((kk*4+half) ^ sw7)<<3));
            #pragma unroll
            for(int mi=0;mi<4;++mi)
                #pragma unroll
                for(int ni=0;ni<4;++ni)
                    acc[mi][ni] = __builtin_amdgcn_mfma_f32_16x16x32_bf16(af[mi], bf[ni], acc[mi][ni], 0,0,0);
        }
        __syncthreads();
    }
    #pragma unroll
    for(int mi=0;mi<4;++mi)
        #pragma unroll
        for(int ni=0;ni<4;++ni)
            #pragma unroll
            for(int j=0;j<4;++j){
                int row = m0 + wm*64 + mi*16 + half*4 + j;
                int col = n0 + wn*64 + ni*16 + q16;
                out[(size_t)row*HIDDEN + col] = acc[mi][ni][j] + bias[col];
            }
}

// flash attention (byte-identical to R23): swapped QK^T 16x16 core, asm-pinned async staging,
// shift-free softmax, 4-buffer LDS rotation with one barrier per 2 kv-tiles.
__global__ __launch_bounds__(512, 2) void k_attn(const unsigned short* __restrict__ Qp,
                                                 const unsigned short* __restrict__ Kp,
                                                 const unsigned short* __restrict__ Vt,
                                                 unsigned short* __restrict__ AO){
    __shared__ __align__(16) unsigned short KV[4][10240];   // 4 x [K 64x80 | V 80x64] = 80 KB
    const int tid  = threadIdx.x;
    const int lane = tid & 63, wid = tid >> 6;              // wid in [0,8)
    const int g    = lane >> 4, q16 = lane & 15;
    const int sw7  = q16 & 7;

    int lb = ((blockIdx.x & 7) << 6) | (blockIdx.x >> 3);   // XCD-chunked (512 = 8*64)
    const int qt = lb & 15, h = (lb >> 4) & 15, b = lb >> 8;
    const int qbase = qt * 256;
    const int bh = b*HEADS + h;

    const unsigned short* kbase = Kp + (size_t)(bh*TT) * DPAD;
    const unsigned short* vbase = Vt + (size_t)(bh*DPAD) * TT;

    // per-thread staging slots: 1280 chunks over 512 threads (3rd iter: tid<256 only, wave-uniform)
    const unsigned short* gp[3]; int lo[3], lo2[3], adv[3];
    #pragma unroll
    for(int i=0;i<3;++i){
        int c = tid + i*512; if(c > 1279) c = 1279;          // clamped; guarded at use
        if(c < 640){
            int r = c/10, ch = c - r*10;
            int phys = (ch < 8) ? (ch ^ (r&7)) : (8 + ((ch&1) ^ (r&1)));
            lo[i]  = r*KSTR2 + (phys<<3);
            lo2[i] = lo[i];
            gp[i]  = kbase + (size_t)r*DPAD + ch*8;
            adv[i] = 64*DPAD;
        } else {
            int c2 = c - 640, d = c2>>3, ch = c2&7;
            int kh = ch>>2, thi = (ch>>1)&1, g0 = 4*kh + 2*(ch&1);
            lo[i]  = VOFF + d*64 + (((g0  ) ^ (d&7))<<3) + 4*thi;   // kv pairs (w=0..3)
            lo2[i] = VOFF + d*64 + (((g0+1) ^ (d&7))<<3) + 4*thi;   // kv pairs (w=4..7)
            gp[i]  = vbase + (size_t)d*TT + ch*8;
            adv[i] = 64;
        }
    }

    // Q fragments: 2 q-subtiles x 16 rows per wave; B-operand row q=q16, k-slot g*8+e
    bf16x8 qf[2][3];
    #pragma unroll
    for(int u=0;u<2;++u){
        const unsigned short* qptr = Qp + ((size_t)(bh*TT) + qbase + u*128 + wid*16 + q16) * DPAD;
        #pragma unroll
        for(int kk=0;kk<3;++kk) qf[u][kk] = *reinterpret_cast<const bf16x8*>(qptr + kk*32 + g*8);
    }

    f32x4 accO[2][5] = {};
    float l[2] = {0.f, 0.f};                                // per-lane PARTIAL sums (epilogue reduce)
    u32x4 stg[3];

    auto writebuf = [&](int bsel){
        #pragma unroll
        for(int i=0;i<3;++i) if(i<2 || tid<256){
            if(tid + i*512 < 640){
                *reinterpret_cast<u32x4*>(&KV[bsel][lo[i]]) = stg[i];
            } else {
                uint2 a; a.x = stg[i].x; a.y = stg[i].y;
                uint2 bq; bq.x = stg[i].z; bq.y = stg[i].w;
                *reinterpret_cast<uint2*>(&KV[bsel][lo[i]])  = a;
                *reinterpret_cast<uint2*>(&KV[bsel][lo2[i]]) = bq;
            }
            gp[i] += adv[i];
        }
    };
    auto issue = [&](){
        #pragma unroll
        for(int i=0;i<3;++i) if(i<2 || tid<256)
            asm volatile("global_load_dwordx4 %0, %1, off"
                         : "=v"(stg[i]) : "v"(gp[i]) : "memory");
    };
    auto tilecomp = [&](const unsigned short* Kb, const unsigned short* Vb){
        f32x4 s[2][4] = {};
        __builtin_amdgcn_s_setprio(1);
        #pragma unroll
        for(int t=0;t<4;++t){
            const int row = t*16 + q16;
            bf16x8 kf0 = *reinterpret_cast<const bf16x8*>(&Kb[row*KSTR2 + ((g     ^ sw7)<<3)]);
            bf16x8 kf1 = *reinterpret_cast<const bf16x8*>(&Kb[row*KSTR2 + (((4+g) ^ sw7)<<3)]);
            bf16x8 kf2 = *reinterpret_cast<const bf16x8*>(&Kb[row*KSTR2 + ((8 + ((g&1) ^ (row&1)))<<3)]);
            s[0][t] = __builtin_amdgcn_mfma_f32_16x16x32_bf16(kf0, qf[0][0], s[0][t], 0,0,0);
            s[1][t] = __builtin_amdgcn_mfma_f32_16x16x32_bf16(kf0, qf[1][0], s[1][t], 0,0,0);
            s[0][t] = __builtin_amdgcn_mfma_f32_16x16x32_bf16(kf1, qf[0][1], s[0][t], 0,0,0);
            s[1][t] = __builtin_amdgcn_mfma_f32_16x16x32_bf16(kf1, qf[1][1], s[1][t], 0,0,0);
            s[0][t] = __builtin_amdgcn_mfma_f32_16x16x32_bf16(kf2, qf[0][2], s[0][t], 0,0,0);
            s[1][t] = __builtin_amdgcn_mfma_f32_16x16x32_bf16(kf2, qf[1][2], s[1][t], 0,0,0);
        }
        __builtin_amdgcn_s_setprio(0);

        bf16x8 pf[2][2];
        #pragma unroll
        for(int u=0;u<2;++u){
            unsigned dwA[4], dwB[4];
            float sum = 0.f;
            #pragma unroll
            for(int t4=0;t4<4;++t4){
                float p0 = __builtin_amdgcn_exp2f(s[u][t4][0]);
                float p1 = __builtin_amdgcn_exp2f(s[u][t4][1]);
                float p2 = __builtin_amdgcn_exp2f(s[u][t4][2]);
                float p3 = __builtin_amdgcn_exp2f(s[u][t4][3]);
                sum += (p0 + p1) + (p2 + p3);
                dwA[t4] = pkbf(p0, p1);
                dwB[t4] = pkbf(p2, p3);
            }
            l[u] += sum;
            union { unsigned w[4]; bf16x8 v; } pu0, pu1;
            pu0.w[0]=dwA[0]; pu0.w[1]=dwB[0]; pu0.w[2]=dwA[1]; pu0.w[3]=dwB[1];
            pu1.w[0]=dwA[2]; pu1.w[1]=dwB[2]; pu1.w[2]=dwA[3]; pu1.w[3]=dwB[3];
            pf[u][0] = pu0.v;  pf[u][1] = pu1.v;
        }

        __builtin_amdgcn_s_setprio(1);
        #pragma unroll
        for(int kh=0; kh<2; ++kh)
            #pragma unroll
            for(int nt=0; nt<5; ++nt){
                bf16x8 vf = *reinterpret_cast<const bf16x8*>(&Vb[(nt*16+q16)*64 + (((kh*4+g) ^ sw7)<<3)]);
                accO[0][nt] = __builtin_amdgcn_mfma_f32_16x16x32_bf16(pf[0][kh], vf, accO[0][nt], 0,0,0);
                accO[1][nt] = __builtin_amdgcn_mfma_f32_16x16x32_bf16(pf[1][kh], vf, accO[1][nt], 0,0,0);
            }
        __builtin_amdgcn_s_setprio(0);
    };

    // prologue: stage tiles 0,1 into bufs 0,1
    #pragma unroll
    for(int i=0;i<3;++i) if(i<2 || tid<256) stg[i] = *reinterpret_cast<const u32x4*>(gp[i]);
    writebuf(0);
    #pragma unroll
    for(int i=0;i<3;++i) if(i<2 || tid<256) stg[i] = *reinterpret_cast<const u32x4*>(gp[i]);
    writebuf(1);
    __syncthreads();

    for(int kt2 = 0; kt2 < 32; ++kt2){
        const int t0 = 2*kt2;
        const int b0 = t0 & 3, b1 = (t0+1) & 3, b2 = (t0+2) & 3, b3 = (t0+3) & 3;
        const bool more = (kt2 < 31);
        if(more) issue();                               // loads for tile t0+2

        tilecomp(KV[b0], KV[b0] + VOFF);

        if(more){
            asm volatile("s_waitcnt vmcnt(0)" ::: "memory");
            __builtin_amdgcn_sched_barrier(0);
            writebuf(b2);                               // b2 != b0,b1 (differs by 2)
            issue();                                    // loads for tile t0+3
        }

        tilecomp(KV[b1], KV[b1] + VOFF);

        if(more){
            asm volatile("s_waitcnt vmcnt(0)" ::: "memory");
            __builtin_amdgcn_sched_barrier(0);
            writebuf(b3);                               // b3 != b0,b1
        }
        __syncthreads();                                // fences next round's writes to b0,b1
    }

    // epilogue: reduce per-lane partial l across the 4 lanes sharing q, then normalize
    #pragma unroll
    for(int u=0;u<2;++u){
        float lt = l[u];
        lt += __shfl_xor(lt, 16, 64);
        lt += __shfl_xor(lt, 32, 64);
        float linv[4];
        #pragma unroll
        for(int j=0;j<4;++j){
            float lj = __shfl(lt, (lane & 48) | (4*g + j), 64);
            linv[j] = 1.0f / lj;
        }
        #pragma unroll
        for(int nt=0;nt<5;++nt){
            int d = nt*16 + q16;
            if(d < HDIM){
                #pragma unroll
                for(int j=0;j<4;++j){
                    int t = qbase + u*128 + wid*16 + 4*g + j;
                    AO[((size_t)(b*TT + t))*HIDDEN + h*HDIM + d] = f2b(accO[u][nt][j] * linv[j]);
                }
            }
        }
    }
}

extern "C" void kernel_launch(void* const* d_in, const int* in_sizes, int n_in,
                              void* d_out, int out_size, void* d_ws, size_t ws_size,
                              hipStream_t stream) {
    const float* x  = (const float*)d_in[0];
    const float* wq = (const float*)d_in[1];
    const float* bq = (const float*)d_in[2];
    const float* wk = (const float*)d_in[3];
    const float* bk = (const float*)d_in[4];
    const float* wv = (const float*)d_in[5];
    const float* bv = (const float*)d_in[6];
    const float* wo = (const float*)d_in[7];
    const float* bo = (const float*)d_in[8];

    char* ws = (char*)d_ws;
    const size_t szXb = (size_t)BT*HIDDEN*2;          // 18874368
    const size_t szW  = (size_t)HIDDEN*HIDDEN*2;      // 2654208
    const size_t szQp = (size_t)NB*HEADS*TT*DPAD*2;   // 25165824

    unsigned short* Xb  = (unsigned short*)(ws);
    unsigned short* WTq = (unsigned short*)(ws + szXb);   // WTq|WTk|WTv|WTo contiguous
    unsigned short* WTo = (unsigned short*)(ws + szXb + 3*szW);
    unsigned short* Qp  = (unsigned short*)(ws + szXb + 4*szW);
    unsigned short* Kp  = (unsigned short*)(ws + szXb + 4*szW + szQp);
    unsigned short* Vt  = (unsigned short*)(ws + szXb + 4*szW + 2*szQp);
    unsigned short* AO  = (unsigned short*)(ws + szXb + 4*szW + 3*szQp);

    k_convert_x<<<BT*HIDDEN/1024, 256, 0, stream>>>(x, Xb);
    k_padzero<<<512, 256, 0, stream>>>(Qp, Kp);       // targeted pad zeros
    k_wtrans<<<1296, 256, 0, stream>>>(wq, wk, wv, wo, WTq);

    const float qscale = (1.0f / sqrtf(72.0f)) * 1.44269504f;  // fold log2(e) for exp2 softmax
    k_gemm_qkv<<<1728, 256, 0, stream>>>(Xb, WTq, bq, bk, bv, Qp, Kp, Vt, qscale);

    k_attn<<<NB*HEADS*(TT/256), 512, 0, stream>>>(Qp, Kp, Vt, AO);

    k_gemm_o<<<576, 256, 0, stream>>>(AO, WTo, bo, (float*)d_out);
}

// Round 25
// 306.939 us; speedup vs baseline: 1.0411x; 1.0411x over previous
//
#include <hip/hip_runtime.h>

#define HIDDEN 1152
#define HEADS  16
#define HDIM   72
#define DPAD   96
#define NB     2
#define TT     4096
#define BT     (NB*TT)  // 8192

#define KSTR2  80      // attn K-tile row stride (shorts)
#define VOFF   5120    // attn V offset inside KV buffer (shorts)

typedef float  f32x4   __attribute__((ext_vector_type(4)));
typedef __bf16 bf16x8  __attribute__((ext_vector_type(8)));
typedef unsigned u32x4 __attribute__((ext_vector_type(4)));

static __device__ __forceinline__ unsigned pkbf(float a, float b){
    unsigned r;
    asm("v_cvt_pk_bf16_f32 %0, %1, %2" : "=v"(r) : "v"(a), "v"(b));
    return r;
}
static __device__ __forceinline__ unsigned short f2b(float f){
    return (unsigned short)pkbf(f, f);
}
static __device__ __forceinline__ void gld16(const unsigned short* g, unsigned short* l){
    __builtin_amdgcn_global_load_lds((const __attribute__((address_space(1))) void*)g,
                                     (__attribute__((address_space(3))) void*)l, 16, 0, 0);
}

__global__ __launch_bounds__(256) void k_convert_x(const float* __restrict__ x, unsigned short* __restrict__ xb){
    int i = (blockIdx.x*256 + threadIdx.x) * 4;
    float4 v = *reinterpret_cast<const float4*>(x + i);
    uint2 p; p.x = pkbf(v.x, v.y); p.y = pkbf(v.z, v.w);
    *reinterpret_cast<uint2*>(xb + i) = p;
}

// targeted pad-zeroing: Q d in [80,96) and K d in [72,80) (V pads feed discarded outputs)
__global__ __launch_bounds__(256) void k_padzero(unsigned short* __restrict__ Qp,
                                                 unsigned short* __restrict__ Kp){
    int row = blockIdx.x*256 + threadIdx.x;       // 131072 rows
    uint4 z = {0,0,0,0};
    unsigned short* q = Qp + (size_t)row*DPAD + 80;
    *reinterpret_cast<uint4*>(q)     = z;
    *reinterpret_cast<uint4*>(q + 8) = z;
    *reinterpret_cast<uint4*>(Kp + (size_t)row*DPAD + 72) = z;
}

// fused tiled transpose+convert for all 4 weights: w[k][n] (fp32) -> wt[n][k] (bf16)
__global__ __launch_bounds__(256) void k_wtrans(const float* __restrict__ wq, const float* __restrict__ wk,
                                                const float* __restrict__ wv, const float* __restrict__ wo,
                                                unsigned short* __restrict__ wt0){
    __shared__ __align__(16) unsigned short Ws[64][72];
    const int wi = blockIdx.x / 324, bi = blockIdx.x % 324;
    const float* w = wi==0 ? wq : (wi==1 ? wk : (wi==2 ? wv : wo));
    unsigned short* wt = wt0 + (size_t)wi*HIDDEN*HIDDEN;
    const int r0 = (bi / 18) * 64, c0 = (bi % 18) * 64;
    #pragma unroll
    for(int it=0; it<4; ++it){
        int idx = threadIdx.x + it*256;
        int r = idx >> 4, cq = (idx & 15) * 4;
        float4 v = *reinterpret_cast<const float4*>(w + (size_t)(r0+r)*HIDDEN + c0 + cq);
        uint2 p; p.x = pkbf(v.x, v.y); p.y = pkbf(v.z, v.w);
        *reinterpret_cast<uint2*>(&Ws[r][cq]) = p;
    }
    __syncthreads();
    #pragma unroll
    for(int it=0; it<4; ++it){
        int idx = threadIdx.x + it*256;
        int rr = idx >> 4, cq = (idx & 15) * 4;
        ushort4 o;
        o.x = Ws[cq+0][rr]; o.y = Ws[cq+1][rr]; o.z = Ws[cq+2][rr]; o.w = Ws[cq+3][rr];
        *reinterpret_cast<ushort4*>(wt + (size_t)(c0+rr)*HIDDEN + r0 + cq) = o;
    }
}

// Fused QKV GEMM, BK=64 (R23 version): A = Xb [8192][1152], B^T = WT [3456][1152].
__global__ __launch_bounds__(256, 3) void k_gemm_qkv(const unsigned short* __restrict__ A,
                                                     const unsigned short* __restrict__ WT,
                                                     const float* __restrict__ bq,
                                                     const float* __restrict__ bk,
                                                     const float* __restrict__ bv,
                                                     unsigned short* __restrict__ Qp,
                                                     unsigned short* __restrict__ Kp,
                                                     unsigned short* __restrict__ Vt,
                                                     float qscale){
    __shared__ __align__(16) unsigned short S[16384];         // As[8192] | Bs[8192]; V-epilogue aliases
    unsigned short* As = S;
    unsigned short* Bs = S + 8192;
    const int tid = threadIdx.x, lane = tid & 63, wid = tid >> 6;
    const int wm = wid >> 1, wn = wid & 1;
    const int half = lane >> 4, q16 = lane & 15;
    const int sw7 = q16 & 7;
    int lb = (blockIdx.x & 7) * 216 + (blockIdx.x >> 3);      // XCD-chunked swizzle (1728 = 8*216)
    const int m0 = (lb / 27) * 128;
    const int t9 = lb % 27;
    const int which = t9 / 9;                                  // 0=Q 1=K 2=V (block-uniform)
    const int n0g = t9 * 128;
    const int cc0 = (t9 % 9) * 128;
    const float* bias = which==0 ? bq : (which==1 ? bk : bv);
    const float scale = which==0 ? qscale : 1.0f;

    size_t aoff[4], boff[4];
    #pragma unroll
    for(int it=0; it<4; ++it){
        int c = tid + it*256;
        int row = c >> 3, ph = c & 7;
        int gsrc = ph ^ (row & 7);
        aoff[it] = (size_t)(m0  + row)*HIDDEN + gsrc*8;
        boff[it] = (size_t)(n0g + row)*HIDDEN + gsrc*8;
    }

    f32x4 acc[4][4] = {};
    for(int k0 = 0; k0 < HIDDEN; k0 += 64){
        #pragma unroll
        for(int it=0; it<4; ++it) gld16(A  + aoff[it] + k0, As + (tid + it*256)*8);
        #pragma unroll
        for(int it=0; it<4; ++it) gld16(WT + boff[it] + k0, Bs + (tid + it*256)*8);
        __syncthreads();
        #pragma unroll
        for(int kk=0; kk<2; ++kk){
            bf16x8 af[4], bf[4];
            #pragma unroll
            for(int mi=0;mi<4;++mi)
                af[mi] = *reinterpret_cast<const bf16x8*>(As + (wm*64+mi*16+q16)*64 + (((kk*4+half) ^ sw7)<<3));
            #pragma unroll
            for(int ni=0;ni<4;++ni)
                bf[ni] = *reinterpret_cast<const bf16x8*>(Bs + (wn*64+ni*16+q16)*64 + (((kk*4+half) ^ sw7)<<3));
            #pragma unroll
            for(int mi=0;mi<4;++mi)
                #pragma unroll
                for(int ni=0;ni<4;++ni)
                    acc[mi][ni] = __builtin_amdgcn_mfma_f32_16x16x32_bf16(af[mi], bf[ni], acc[mi][ni], 0,0,0);
        }
        __syncthreads();
    }
    if(which < 2){
        unsigned short* outp = which==0 ? Qp : Kp;
        #pragma unroll
        for(int mi=0;mi<4;++mi)
            #pragma unroll
            for(int ni=0;ni<4;++ni)
                #pragma unroll
                for(int j=0;j<4;++j){
                    int row = m0 + wm*64 + mi*16 + half*4 + j;
                    int col = cc0 + wn*64 + ni*16 + q16;
                    float v = (acc[mi][ni][j] + bias[col]) * scale;
                    int bb = row >> 12, t = row & 4095;
                    int hh = col / HDIM, d = col % HDIM;
                    outp[((size_t)((bb*HEADS + hh)*TT) + t)*DPAD + d] = f2b(v);
                }
    } else {
        // V: transpose 128x128 tile through LDS (two 64-row passes) for coalesced [d][t] stores
        #pragma unroll
        for(int ph=0; ph<2; ++ph){
            if(wm == ph){
                #pragma unroll
                for(int mi=0;mi<4;++mi)
                    #pragma unroll
                    for(int ni=0;ni<4;++ni)
                        #pragma unroll
                        for(int j=0;j<4;++j){
                            int rloc = mi*16 + half*4 + j;
                            int cloc = wn*64 + ni*16 + q16;
                            float v = acc[mi][ni][j] + bias[cc0 + cloc];
                            S[cloc*64 + (rloc ^ ((cloc&7)<<3))] = f2b(v);
                        }
            }
            __syncthreads();
            {
                int col = tid >> 1, seg = tid & 1;
                int gcol = cc0 + col, hh = gcol / HDIM, d = gcol % HDIM;
                int grow = m0 + ph*64 + seg*32;
                int bb = grow >> 12, t0 = grow & 4095;
                unsigned short* dst = Vt + ((size_t)((bb*HEADS + hh)*DPAD) + d)*TT + t0;
                #pragma unroll
                for(int kg=0; kg<4; ++kg){
                    uint4 v = *reinterpret_cast<const uint4*>(&S[col*64 + ((seg*32 + kg*8) ^ ((col&7)<<3))]);
                    *reinterpret_cast<uint4*>(dst + kg*8) = v;
                }
            }
            __syncthreads();
        }
    }
}

// O-projection GEMM, BK=64 (R23 version): fp32 out + bias
__global__ __launch_bounds__(256, 3) void k_gemm_o(const unsigned short* __restrict__ A,
                                                   const unsigned short* __restrict__ Bt,
                                                   const float* __restrict__ bias,
                                                   float* __restrict__ out){
    __shared__ __align__(16) unsigned short As[8192];
    __shared__ __align__(16) unsigned short Bs[8192];
    const int tid = threadIdx.x, lane = tid & 63, wid = tid >> 6;
    const int wm = wid >> 1, wn = wid & 1;
    const int half = lane >> 4, q16 = lane & 15;
    const int sw7 = q16 & 7;
    int lb = (blockIdx.x & 7) * 72 + (blockIdx.x >> 3);       // XCD-chunked swizzle (576 = 8*72)
    const int n0 = (lb % 9) * 128, m0 = (lb / 9) * 128;

    size_t aoff[4], boff[4];
    #pragma unroll
    for(int it=0; it<4; ++it){
        int c = tid + it*256;
        int row = c >> 3, ph = c & 7;
        int gsrc = ph ^ (row & 7);
        aoff[it] = (size_t)(m0 + row)*HIDDEN + gsrc*8;
        boff[it] = (size_t)(n0 + row)*HIDDEN + gsrc*8;
    }

    f32x4 acc[4][4] = {};
    for(int k0 = 0; k0 < HIDDEN; k0 += 64){
        #pragma unroll
        for(int it=0; it<4; ++it) gld16(A  + aoff[it] + k0, As + (tid + it*256)*8);
        #pragma unroll
        for(int it=0; it<4; ++it) gld16(Bt + boff[it] + k0, Bs + (tid + it*256)*8);
        __syncthreads();
        #pragma unroll
        for(int kk=0; kk<2; ++kk){
            bf16x8 af[4], bf[4];
            #pragma unroll
            for(int mi=0;mi<4;++mi)
                af[mi] = *reinterpret_cast<const bf16x8*>(As + (wm*64+mi*16+q16)*64 + (((kk*4+half) ^ sw7)<<3));
            #pragma unroll
            for(int ni=0;ni<4;++ni)
                bf[ni] = *reinterpret_cast<const bf16x8*>(Bs + (wn*64+ni*16+q16)*64 + (((kk*4+half) ^ sw7)<<3));
            #pragma unroll
            for(int mi=0;mi<4;++mi)
                #pragma unroll
                for(int ni=0;ni<4;++ni)
                    acc[mi][ni] = __builtin_amdgcn_mfma_f32_16x16x32_bf16(af[mi], bf[ni], acc[mi][ni], 0,0,0);
        }
        __syncthreads();
    }
    #pragma unroll
    for(int mi=0;mi<4;++mi)
        #pragma unroll
        for(int ni=0;ni<4;++ni)
            #pragma unroll
            for(int j=0;j<4;++j){
                int row = m0 + wm*64 + mi*16 + half*4 + j;
                int col = n0 + wn*64 + ni*16 + q16;
                out[(size_t)row*HIDDEN + col] = acc[mi][ni][j] + bias[col];
            }
}

// flash attention (R23): swapped QK^T 16x16 core, asm-pinned async staging, shift-free softmax,
// 4-buffer LDS rotation with one barrier per 2 kv-tiles.
__global__ __launch_bounds__(512, 2) void k_attn(const unsigned short* __restrict__ Qp,
                                                 const unsigned short* __restrict__ Kp,
                                                 const unsigned short* __restrict__ Vt,
                                                 unsigned short* __restrict__ AO){
    __shared__ __align__(16) unsigned short KV[4][10240];   // 4 x [K 64x80 | V 80x64] = 80 KB
    const int tid  = threadIdx.x;
    const int lane = tid & 63, wid = tid >> 6;              // wid in [0,8)
    const int g    = lane >> 4, q16 = lane & 15;
    const int sw7  = q16 & 7;

    int lb = ((blockIdx.x & 7) << 6) | (blockIdx.x >> 3);   // XCD-chunked (512 = 8*64)
    const int qt = lb & 15, h = (lb >> 4) & 15, b = lb >> 8;
    const int qbase = qt * 256;
    const int bh = b*HEADS + h;

    const unsigned short* kbase = Kp + (size_t)(bh*TT) * DPAD;
    const unsigned short* vbase = Vt + (size_t)(bh*DPAD) * TT;

    // per-thread staging slots: 1280 chunks over 512 threads (3rd iter: tid<256 only, wave-uniform)
    const unsigned short* gp[3]; int lo[3], lo2[3], adv[3];
    #pragma unroll
    for(int i=0;i<3;++i){
        int c = tid + i*512; if(c > 1279) c = 1279;          // clamped; guarded at use
        if(c < 640){
            int r = c/10, ch = c - r*10;
            int phys = (ch < 8) ? (ch ^ (r&7)) : (8 + ((ch&1) ^ (r&1)));
            lo[i]  = r*KSTR2 + (phys<<3);
            lo2[i] = lo[i];
            gp[i]  = kbase + (size_t)r*DPAD + ch*8;
            adv[i] = 64*DPAD;
        } else {
            int c2 = c - 640, d = c2>>3, ch = c2&7;
            int kh = ch>>2, thi = (ch>>1)&1, g0 = 4*kh + 2*(ch&1);
            lo[i]  = VOFF + d*64 + (((g0  ) ^ (d&7))<<3) + 4*thi;   // kv pairs (w=0..3)
            lo2[i] = VOFF + d*64 + (((g0+1) ^ (d&7))<<3) + 4*thi;   // kv pairs (w=4..7)
            gp[i]  = vbase + (size_t)d*TT + ch*8;
            adv[i] = 64;
        }
    }

    // Q fragments: 2 q-subtiles x 16 rows per wave; B-operand row q=q16, k-slot g*8+e
    bf16x8 qf[2][3];
    #pragma unroll
    for(int u=0;u<2;++u){
        const unsigned short* qptr = Qp + ((size_t)(bh*TT) + qbase + u*128 + wid*16 + q16) * DPAD;
        #pragma unroll
        for(int kk=0;kk<3;++kk) qf[u][kk] = *reinterpret_cast<const bf16x8*>(qptr + kk*32 + g*8);
    }

    f32x4 accO[2][5] = {};
    float l[2] = {0.f, 0.f};                                // per-lane PARTIAL sums (epilogue reduce)
    u32x4 stg[3];

    auto writebuf = [&](int bsel){
        #pragma unroll
        for(int i=0;i<3;++i) if(i<2 || tid<256){
            if(tid + i*512 < 640){
                *reinterpret_cast<u32x4*>(&KV[bsel][lo[i]]) = stg[i];
            } else {
                uint2 a; a.x = stg[i].x; a.y = stg[i].y;
                uint2 bq; bq.x = stg[i].z; bq.y = stg[i].w;
                *reinterpret_cast<uint2*>(&KV[bsel][lo[i]])  = a;
                *reinterpret_cast<uint2*>(&KV[bsel][lo2[i]]) = bq;
            }
            gp[i] += adv[i];
        }
    };
    auto issue = [&](){
        #pragma unroll
        for(int i=0;i<3;++i) if(i<2 || tid<256)
            asm volatile("global_load_dwordx4 %0, %1, off"
                         : "=v"(stg[i]) : "v"(gp[i]) : "memory");
    };
    auto tilecomp = [&](const unsigned short* Kb, const unsigned short* Vb){
        f32x4 s[2][4] = {};
        __builtin_amdgcn_s_setprio(1);
        #pragma unroll
        for(int t=0;t<4;++t){
            const int row = t*16 + q16;
            bf16x8 kf0 = *reinterpret_cast<const bf16x8*>(&Kb[row*KSTR2 + ((g     ^ sw7)<<3)]);
            bf16x8 kf1 = *reinterpret_cast<const bf16x8*>(&Kb[row*KSTR2 + (((4+g) ^ sw7)<<3)]);
            bf16x8 kf2 = *reinterpret_cast<const bf16x8*>(&Kb[row*KSTR2 + ((8 + ((g&1) ^ (row&1)))<<3)]);
            s[0][t] = __builtin_amdgcn_mfma_f32_16x16x32_bf16(kf0, qf[0][0], s[0][t], 0,0,0);
            s[1][t] = __builtin_amdgcn_mfma_f32_16x16x32_bf16(kf0, qf[1][0], s[1][t], 0,0,0);
            s[0][t] = __builtin_amdgcn_mfma_f32_16x16x32_bf16(kf1, qf[0][1], s[0][t], 0,0,0);
            s[1][t] = __builtin_amdgcn_mfma_f32_16x16x32_bf16(kf1, qf[1][1], s[1][t], 0,0,0);
            s[0][t] = __builtin_amdgcn_mfma_f32_16x16x32_bf16(kf2, qf[0][2], s[0][t], 0,0,0);
            s[1][t] = __builtin_amdgcn_mfma_f32_16x16x32_bf16(kf2, qf[1][2], s[1][t], 0,0,0);
        }
        __builtin_amdgcn_s_setprio(0);

        bf16x8 pf[2][2];
        #pragma unroll
        for(int u=0;u<2;++u){
            unsigned dwA[4], dwB[4];
            float sum = 0.f;
            #pragma unroll
            for(int t4=0;t4<4;++t4){
                float p0 = __builtin_amdgcn_exp2f(s[u][t4][0]);
                float p1 = __builtin_amdgcn_exp2f(s[u][t4][1]);
                float p2 = __builtin_amdgcn_exp2f(s[u][t4][2]);
                float p3 = __builtin_amdgcn_exp2f(s[u][t4][3]);
                sum += (p0 + p1) + (p2 + p3);
                dwA[t4] = pkbf(p0, p1);
                dwB[t4] = pkbf(p2, p3);
            }
            l[u] += sum;
            union { unsigned w[4]; bf16x8 v; } pu0, pu1;
            pu0.w[0]=dwA[0]; pu0.w[1]=dwB[0]; pu0.w[2]=dwA[1]; pu0.w[3]=dwB[1];
            pu1.w[0]=dwA[2]; pu1.w[1]=dwB[2]; pu1.w[2]=dwA[3]; pu1.w[3]=dwB[3];
            pf[u][0] = pu0.v;  pf[u][1] = pu1.v;
        }

        __builtin_amdgcn_s_setprio(1);
        #pragma unroll
        for(int kh=0; kh<2; ++kh)
            #pragma unroll
            for(int nt=0; nt<5; ++nt){
                bf16x8 vf = *reinterpret_cast<const bf16x8*>(&Vb[(nt*16+q16)*64 + (((kh*4+g) ^ sw7)<<3)]);
                accO[0][nt] = __builtin_amdgcn_mfma_f32_16x16x32_bf16(pf[0][kh], vf, accO[0][nt], 0,0,0);
                accO[1][nt] = __builtin_amdgcn_mfma_f32_16x16x32_bf16(pf[1][kh], vf, accO[1][nt], 0,0,0);
            }
        __builtin_amdgcn_s_setprio(0);
    };

    // prologue: stage tiles 0,1 into bufs 0,1
    #pragma unroll
    for(int i=0;i<3;++i) if(i<2 || tid<256) stg[i] = *reinterpret_cast<const u32x4*>(gp[i]);
    writebuf(0);
    #pragma unroll
    for(int i=0;i<3;++i) if(i<2 || tid<256) stg[i] = *reinterpret_cast<const u32x4*>(gp[i]);
    writebuf(1);
    __syncthreads();

    for(int kt2 = 0; kt2 < 32; ++kt2){
        const int t0 = 2*kt2;
        const int b0 = t0 & 3, b1 = (t0+1) & 3, b2 = (t0+2) & 3, b3 = (t0+3) & 3;
        const bool more = (kt2 < 31);
        if(more) issue();                               // loads for tile t0+2

        tilecomp(KV[b0], KV[b0] + VOFF);

        if(more){
            asm volatile("s_waitcnt vmcnt(0)" ::: "memory");
            __builtin_amdgcn_sched_barrier(0);
            writebuf(b2);                               // b2 != b0,b1 (differs by 2)
            issue();                                    // loads for tile t0+3
        }

        tilecomp(KV[b1], KV[b1] + VOFF);

        if(more){
            asm volatile("s_waitcnt vmcnt(0)" ::: "memory");
            __builtin_amdgcn_sched_barrier(0);
            writebuf(b3);                               // b3 != b0,b1
        }
        __syncthreads();                                // fences next round's writes to b0,b1
    }

    // epilogue: reduce per-lane partial l across the 4 lanes sharing q, then normalize
    #pragma unroll
    for(int u=0;u<2;++u){
        float lt = l[u];
        lt += __shfl_xor(lt, 16, 64);
        lt += __shfl_xor(lt, 32, 64);
        float linv[4];
        #pragma unroll
        for(int j=0;j<4;++j){
            float lj = __shfl(lt, (lane & 48) | (4*g + j), 64);
            linv[j] = 1.0f / lj;
        }
        #pragma unroll
        for(int nt=0;nt<5;++nt){
            int d = nt*16 + q16;
            if(d < HDIM){
                #pragma unroll
                for(int j=0;j<4;++j){
                    int t = qbase + u*128 + wid*16 + 4*g + j;
                    AO[((size_t)(b*TT + t))*HIDDEN + h*HDIM + d] = f2b(accO[u][nt][j] * linv[j]);
                }
            }
        }
    }
}

extern "C" void kernel_launch(void* const* d_in, const int* in_sizes, int n_in,
                              void* d_out, int out_size, void* d_ws, size_t ws_size,
                              hipStream_t stream) {
    const float* x  = (const float*)d_in[0];
    const float* wq = (const float*)d_in[1];
    const float* bq = (const float*)d_in[2];
    const float* wk = (const float*)d_in[3];
    const float* bk = (const float*)d_in[4];
    const float* wv = (const float*)d_in[5];
    const float* bv = (const float*)d_in[6];
    const float* wo = (const float*)d_in[7];
    const float* bo = (const float*)d_in[8];

    char* ws = (char*)d_ws;
    const size_t szXb = (size_t)BT*HIDDEN*2;          // 18874368
    const size_t szW  = (size_t)HIDDEN*HIDDEN*2;      // 2654208
    const size_t szQp = (size_t)NB*HEADS*TT*DPAD*2;   // 25165824

    unsigned short* Xb  = (unsigned short*)(ws);
    unsigned short* WTq = (unsigned short*)(ws + szXb);   // WTq|WTk|WTv|WTo contiguous
    unsigned short* WTo = (unsigned short*)(ws + szXb + 3*szW);
    unsigned short* Qp  = (unsigned short*)(ws + szXb + 4*szW);
    unsigned short* Kp  = (unsigned short*)(ws + szXb + 4*szW + szQp);
    unsigned short* Vt  = (unsigned short*)(ws + szXb + 4*szW + 2*szQp);
    unsigned short* AO  = (unsigned short*)(ws + szXb + 4*szW + 3*szQp);

    k_convert_x<<<BT*HIDDEN/1024, 256, 0, stream>>>(x, Xb);
    k_padzero<<<512, 256, 0, stream>>>(Qp, Kp);       // targeted pad zeros
    k_wtrans<<<1296, 256, 0, stream>>>(wq, wk, wv, wo, WTq);

    const float qscale = (1.0f / sqrtf(72.0f)) * 1.44269504f;  // fold log2(e) for exp2 softmax
    k_gemm_qkv<<<1728, 256, 0, stream>>>(Xb, WTq, bq, bk, bv, Qp, Kp, Vt, qscale);

    k_attn<<<NB*HEADS*(TT/256), 512, 0, stream>>>(Qp, Kp, Vt, AO);

    k_gemm_o<<<576, 256, 0, stream>>>(AO, WTo, bo, (float*)d_out);
}